// Round 9
// baseline (6452.736 us; speedup 1.0000x reference)
//
#include <hip/hip_runtime.h>
#include <math.h>

#define BATCH 4
#define NPTS 8192
#define GS 48                     // fine grid 48^3 over [-6,6]^3, cell 0.25
#define NC (GS*GS*GS)             // 110592
#define GMIN (-6.0f)
#define CS 0.25f
#define INVCS 4.0f
#define QG 32                     // coarse Morton grid for query sorting
#define QNC (QG*QG*QG)            // 32768
#define QINV (32.0f/12.0f)
#define FINF 3.4e38f

__device__ __forceinline__ int cellc(float v) {
    int c = (int)((v - GMIN) * INVCS);
    return min(max(c, 0), GS - 1);
}
__device__ __forceinline__ int qcellc(float v) {
    int c = (int)((v - GMIN) * QINV);
    return min(max(c, 0), QG - 1);
}
__device__ __forceinline__ int mort5(int x) {   // spread 5 bits -> every 3rd bit
    return (x & 1) | ((x & 2) << 2) | ((x & 4) << 4) | ((x & 8) << 6) | ((x & 16) << 8);
}
__device__ __forceinline__ void insert3(float d, int idx,
    float& e0, float& e1, float& e2, int& i0, int& i1, int& i2)
{
    bool c0 = d < e0, c1 = d < e1, c2 = d < e2;
    float t1 = __builtin_amdgcn_fmed3f(e0, e1, d);
    float t2 = __builtin_amdgcn_fmed3f(e1, e2, d);
    i2 = c1 ? i1 : (c2 ? idx : i2);
    i1 = c0 ? i0 : (c1 ? idx : i1);
    i0 = c0 ? idx : i0;
    e0 = fminf(e0, d); e1 = t1; e2 = t2;
}

// ---------------------------------------------------------------------------
// K1: histogram candidates (fine linear cells) and queries (coarse Morton).
// ---------------------------------------------------------------------------
__global__ __launch_bounds__(256) void bin_both(
    const float* __restrict__ xyz1, const float* __restrict__ xyz2,
    const float* __restrict__ flow1, int* __restrict__ counts_c,
    int* __restrict__ counts_q)
{
    int t = blockIdx.x * 256 + threadIdx.x;       // 2*BATCH*NPTS threads
    if (t < BATCH * NPTS) {
        int b = t >> 13, n = t & (NPTS - 1);
        const float* x = xyz1 + b * 3 * NPTS + n;
        const float* f = flow1 + b * 3 * NPTS + n;
        float wx = x[0] + f[0], wy = x[NPTS] + f[NPTS], wz = x[2*NPTS] + f[2*NPTS];
        int gc = ((b * GS + cellc(wz)) * GS + cellc(wy)) * GS + cellc(wx);
        atomicAdd(&counts_c[gc], 1);
    } else {
        int tq = t - BATCH * NPTS;
        int b = tq >> 13, n = tq & (NPTS - 1);
        const float* q = xyz2 + b * 3 * NPTS + n;
        int mc = mort5(qcellc(q[0])) | (mort5(qcellc(q[NPTS])) << 1)
               | (mort5(qcellc(q[2*NPTS])) << 2);
        atomicAdd(&counts_q[b * QNC + mc], 1);
    }
}

// ---------------------------------------------------------------------------
// K2: chunked exclusive prefix scan. Blocks 0-3: candidate cells (110592/batch,
// 27 chunks of 4096 via int4); blocks 4-7: query bins (32768/batch, 8 chunks).
// Writes start + cursor. Candidate blocks also write the end sentinel.
// ---------------------------------------------------------------------------
__global__ __launch_bounds__(1024) void scan_chunks(
    const int* __restrict__ cc, int* __restrict__ cs, int* __restrict__ ccur,
    const int* __restrict__ qc, int* __restrict__ qs, int* __restrict__ qcur)
{
    __shared__ int part[1024];
    int blk = blockIdx.x, t = (int)threadIdx.x;
    const int* cnts; int* oS; int* oC; int ncells, batch;
    if (blk < 4) { batch = blk;     cnts = cc; oS = cs; oC = ccur; ncells = NC;  }
    else         { batch = blk - 4; cnts = qc; oS = qs; oC = qcur; ncells = QNC; }

    int base = batch * ncells;
    int carry = batch * NPTS;
    for (int ch = 0; ch < ncells; ch += 4096) {
        int4 v = *(const int4*)&cnts[base + ch + t * 4];
        part[t] = v.x + v.y + v.z + v.w;
        __syncthreads();
        for (int off = 1; off < 1024; off <<= 1) {
            int pv = (t >= off) ? part[t - off] : 0;
            __syncthreads();
            part[t] += pv;
            __syncthreads();
        }
        int excl = carry + ((t > 0) ? part[t - 1] : 0);
        int4 o; o.x = excl; o.y = excl + v.x; o.z = o.y + v.y; o.w = o.z + v.z;
        *(int4*)&oS[base + ch + t * 4] = o;
        *(int4*)&oC[base + ch + t * 4] = o;
        carry += part[1023];
        __syncthreads();
    }
    if (blk < 4 && t == 1023) oS[base + ncells] = carry;   // benign same-value race
}

// ---------------------------------------------------------------------------
// K3: scatter candidates into cell-sorted order (key + flow).
// ---------------------------------------------------------------------------
__global__ __launch_bounds__(256) void scatter_c(
    const float* __restrict__ xyz1, const float* __restrict__ flow1,
    int* __restrict__ ccur, float4* __restrict__ ckey, float4* __restrict__ cflow)
{
    int t = blockIdx.x * 256 + threadIdx.x;
    int b = t >> 13, n = t & (NPTS - 1);
    const float* x = xyz1 + b * 3 * NPTS + n;
    const float* f = flow1 + b * 3 * NPTS + n;
    float fx = f[0], fy = f[NPTS], fz = f[2*NPTS];
    float wx = x[0] + fx, wy = x[NPTS] + fy, wz = x[2*NPTS] + fz;
    float nrm = fmaf(wx, wx, fmaf(wy, wy, wz * wz));
    int gc = ((b * GS + cellc(wz)) * GS + cellc(wy)) * GS + cellc(wx);
    int pos = atomicAdd(&ccur[gc], 1);
    ckey[pos]  = make_float4(-2.0f*wx, -2.0f*wy, -2.0f*wz, nrm);
    cflow[pos] = make_float4(fx, fy, fz, 0.0f);
}

// ---------------------------------------------------------------------------
// K4: scatter queries into Morton-sorted order + Phase A radius bound.
// Rings s=0..2: scan actual points, e2 = 3rd-best key among seen -> tight
// S = floor(sqrt(e2+|q|^2)/CS)+1 (valid upper bound: seen-set 3rd >= true 3rd).
// Sparse fallback: count-only rings, corner bound S = floor(sqrt3*(s+1))+1.
// ---------------------------------------------------------------------------
__global__ __launch_bounds__(256) void scatter_q(
    const float* __restrict__ xyz2, const int* __restrict__ cstart,
    const float4* __restrict__ ckey, int* __restrict__ qcur,
    float4* __restrict__ qpos, int* __restrict__ sarr)
{
    int t = blockIdx.x * 256 + threadIdx.x;
    int b = t >> 13, n = t & (NPTS - 1);
    const float* q = xyz2 + b * 3 * NPTS + n;
    float qx = q[0], qy = q[NPTS], qz = q[2*NPTS];
    float qn = fmaf(qx, qx, fmaf(qy, qy, qz * qz));
    int mc = mort5(qcellc(qx)) | (mort5(qcellc(qy)) << 1) | (mort5(qcellc(qz)) << 2);
    int pos = atomicAdd(&qcur[b * QNC + mc], 1);
    qpos[pos] = make_float4(qx, qy, qz, __int_as_float(n));

    int hx = cellc(qx), hy = cellc(qy), hz = cellc(qz);
    float e0 = FINF, e1 = FINF, e2 = FINF;
    int nf = 0, S = -1;
    for (int s = 0; s <= 2 && S < 0; ++s) {
        for (int z = max(hz-s,0); z <= min(hz+s,GS-1); ++z)
        for (int y = max(hy-s,0); y <= min(hy+s,GS-1); ++y)
        for (int x = max(hx-s,0); x <= min(hx+s,GS-1); ++x) {
            int ch = max(abs(z-hz), max(abs(y-hy), abs(x-hx)));
            if (ch != s) continue;
            int gc = ((b * GS + z) * GS + y) * GS + x;
            int st = cstart[gc], en = cstart[gc + 1];
            nf += en - st;
            for (int k = st; k < en; ++k) {
                float4 c = ckey[k];
                float d = fmaf(c.x, qx, fmaf(c.y, qy, fmaf(c.z, qz, c.w)));
                float t1 = __builtin_amdgcn_fmed3f(e0, e1, d);
                float t2 = __builtin_amdgcn_fmed3f(e1, e2, d);
                e0 = fminf(e0, d); e1 = t1; e2 = t2;
            }
        }
        if (nf >= 3) S = (int)(sqrtf(fmaxf(e2 + qn, 0.0f)) * INVCS) + 1;
    }
    if (S < 0) {
        for (int s = 3; s < GS && S < 0; ++s) {
            for (int z = max(hz-s,0); z <= min(hz+s,GS-1); ++z)
            for (int y = max(hy-s,0); y <= min(hy+s,GS-1); ++y)
            for (int x = max(hx-s,0); x <= min(hx+s,GS-1); ++x) {
                int ch = max(abs(z-hz), max(abs(y-hy), abs(x-hx)));
                if (ch != s) continue;
                int gc = ((b * GS + z) * GS + y) * GS + x;
                nf += cstart[gc + 1] - cstart[gc];
            }
            if (nf >= 3) S = (int)(1.7320508f * (float)(s + 1)) + 1;
        }
        if (S < 0) S = GS;   // unreachable: whole grid holds 8192 >= 3
    }
    sarr[pos] = S;
}

// ---------------------------------------------------------------------------
// K5: exact 3-NN per 64-query tile + fused IDW epilogue.
// Block = 512 threads = 8 waves; lane l = query l of the tile (each wave holds
// all 64 queries); cells of the tile's S-expanded bbox are round-robined
// across waves (cnt&7); candidate reads are lane-uniform -> s_load streaming.
// One LDS merge of the 8 partial top-3s at the end, then epilogue on t<64.
// ---------------------------------------------------------------------------
__global__ __launch_bounds__(512, 4) void knn_tile(
    const float4* __restrict__ qpos, const int* __restrict__ sarr,
    const float4* __restrict__ ckey, const float4* __restrict__ cflow,
    const int* __restrict__ cstart, float* __restrict__ out)
{
    __shared__ float md[8][64][3];
    __shared__ int   mi[8][64][3];

    int tile = blockIdx.x, b = tile >> 7, ti = tile & 127;
    int t = (int)threadIdx.x, w = t >> 6, l = t & 63;
    int qbase = b * NPTS + ti * 64;

    float4 qp = qpos[qbase + l];
    float qx = qp.x, qy = qp.y, qz = qp.z;
    int origj = __float_as_int(qp.w);
    float qn = fmaf(qx, qx, fmaf(qy, qy, qz * qz));
    int S = sarr[qbase + l];

    float bxl=qx, bxh=qx, byl=qy, byh=qy, bzl=qz, bzh=qz;
    int mS = S;
    #pragma unroll
    for (int o = 32; o >= 1; o >>= 1) {
        bxl = fminf(bxl, __shfl_xor(bxl, o));  bxh = fmaxf(bxh, __shfl_xor(bxh, o));
        byl = fminf(byl, __shfl_xor(byl, o));  byh = fmaxf(byh, __shfl_xor(byh, o));
        bzl = fminf(bzl, __shfl_xor(bzl, o));  bzh = fmaxf(bzh, __shfl_xor(bzh, o));
        mS  = max(mS, __shfl_xor(mS, o));
    }
    int lox = max(cellc(bxl) - mS, 0), hix = min(cellc(bxh) + mS, GS - 1);
    int loy = max(cellc(byl) - mS, 0), hiy = min(cellc(byh) + mS, GS - 1);
    int loz = max(cellc(bzl) - mS, 0), hiz = min(cellc(bzh) + mS, GS - 1);

    float e0 = FINF, e1 = FINF, e2 = FINF;
    int   i0 = 0, i1 = 0, i2 = 0;
    int cnt = 0;
    for (int z = loz; z <= hiz; ++z)
    for (int y = loy; y <= hiy; ++y) {
        int rb = ((b * GS + z) * GS + y) * GS;
        for (int x = lox; x <= hix; ++x) {
            if ((cnt++ & 7) != w) continue;
            int gc = rb + x;
            int st = cstart[gc], en = cstart[gc + 1];      // lane-uniform
            for (int k = st; k < en; ++k) {
                float4 c = ckey[k];                         // lane-uniform
                float d = fmaf(c.x, qx, fmaf(c.y, qy, fmaf(c.z, qz, c.w)));
                bool c0 = d < e0, c1 = d < e1, c2 = d < e2;
                float t1 = __builtin_amdgcn_fmed3f(e0, e1, d);
                float t2 = __builtin_amdgcn_fmed3f(e1, e2, d);
                i2 = c1 ? i1 : (c2 ? k : i2);
                i1 = c0 ? i0 : (c1 ? k : i1);
                i0 = c0 ? k : i0;
                e0 = fminf(e0, d); e1 = t1; e2 = t2;
            }
        }
    }
    md[w][l][0] = e0; md[w][l][1] = e1; md[w][l][2] = e2;
    mi[w][l][0] = i0; mi[w][l][1] = i1; mi[w][l][2] = i2;
    __syncthreads();

    if (t < 64) {
        float m0 = FINF, m1 = FINF, m2 = FINF;
        int   n0 = 0, n1 = 0, n2 = 0;
        #pragma unroll
        for (int ww = 0; ww < 8; ++ww) {
            insert3(md[ww][t][0], mi[ww][t][0], m0, m1, m2, n0, n1, n2);
            insert3(md[ww][t][1], mi[ww][t][1], m0, m1, m2, n0, n1, n2);
            insert3(md[ww][t][2], mi[ww][t][2], m0, m1, m2, n0, n1, n2);
        }
        float wsum = 0.f, f2x = 0.f, f2y = 0.f, f2z = 0.f;
        int idxs[3] = { n0, n1, n2 };
        #pragma unroll
        for (int k = 0; k < 3; ++k) {
            int id = idxs[k];
            float4 c = ckey[id];
            float cx = -0.5f*c.x, cy = -0.5f*c.y, cz = -0.5f*c.z;   // exact
            float dx = cx - qx, dy = cy - qy, dz = cz - qz;
            float dist = sqrtf(fmaf(dx, dx, fmaf(dy, dy, dz * dz)));
            dist = fmaxf(dist, 1e-10f);
            float wgt = 1.0f / dist;
            wsum += wgt;
            float4 fl = cflow[id];
            f2x = fmaf(wgt, fl.x, f2x);
            f2y = fmaf(wgt, fl.y, f2y);
            f2z = fmaf(wgt, fl.z, f2z);
        }
        float r = 1.0f / wsum;
        float* ob = out + b * 3 * NPTS;
        ob[origj]            = qx - f2x * r;
        ob[NPTS + origj]     = qy - f2y * r;
        ob[2 * NPTS + origj] = qz - f2z * r;
    }
}

// ---------------------------------------------------------------------------
// Launcher. Workspace (~8.2 MB; ws >= 9.9 MB proven in R7):
// ckey|cflow|counts_c|counts_q|cstart|ccursor|qstart|qcursor|qpos|sarr
// counts_c/counts_q adjacent -> single memset.
// ---------------------------------------------------------------------------
extern "C" void kernel_launch(void* const* d_in, const int* in_sizes, int n_in,
                              void* d_out, int out_size, void* d_ws, size_t ws_size,
                              hipStream_t stream)
{
    const float* xyz1  = (const float*)d_in[0];
    const float* xyz2  = (const float*)d_in[1];
    const float* flow1 = (const float*)d_in[2];
    float* out = (float*)d_out;

    char* p = (char*)d_ws;
    float4* ckey     = (float4*)p;  p += (size_t)BATCH * NPTS * 16;
    float4* cflow    = (float4*)p;  p += (size_t)BATCH * NPTS * 16;
    int*    counts_c = (int*)p;     p += (size_t)BATCH * NC * 4;
    int*    counts_q = (int*)p;     p += (size_t)BATCH * QNC * 4;
    int*    cstart   = (int*)p;     p += ((size_t)BATCH * NC + 4) * 4;
    int*    ccursor  = (int*)p;     p += (size_t)BATCH * NC * 4;
    int*    qstart   = (int*)p;     p += (size_t)BATCH * QNC * 4;
    int*    qcursor  = (int*)p;     p += (size_t)BATCH * QNC * 4;
    float4* qpos     = (float4*)p;  p += (size_t)BATCH * NPTS * 16;
    int*    sarr     = (int*)p;

    hipMemsetAsync(counts_c, 0, (size_t)BATCH * (NC + QNC) * 4, stream);
    bin_both   <<<2 * BATCH * NPTS / 256, 256, 0, stream>>>(xyz1, xyz2, flow1, counts_c, counts_q);
    scan_chunks<<<8, 1024, 0, stream>>>(counts_c, cstart, ccursor, counts_q, qstart, qcursor);
    scatter_c  <<<BATCH * NPTS / 256, 256, 0, stream>>>(xyz1, flow1, ccursor, ckey, cflow);
    scatter_q  <<<BATCH * NPTS / 256, 256, 0, stream>>>(xyz2, cstart, ckey, qcursor, qpos, sarr);
    knn_tile   <<<BATCH * NPTS / 64, 512, 0, stream>>>(qpos, sarr, ckey, cflow, cstart, out);
}

// Round 10
// 260.720 us; speedup vs baseline: 24.7497x; 24.7497x over previous
//
#include <hip/hip_runtime.h>
#include <math.h>

#define BATCH 4
#define NPTS 8192
#define GS 24                  // 24^3 cells of 0.5 over [-6,6]^3
#define NCP 16384              // padded cells per batch (24^3 = 13824)
#define GMIN (-6.0f)
#define CS 0.5f
#define INVCS 2.0f
#define FINF 3.4e38f
#define NSEG 8                 // segments in knn_tile & fallback
#define CHN 512                // LDS chunk slots
#define FSEGLEN (NPTS / NSEG)  // 1024

__device__ __forceinline__ int cellc(float v) {
    int c = (int)((v - GMIN) * INVCS);
    return min(max(c, 0), GS - 1);
}

// branchless sorted top-3 update (R5-proven). Strict '<': incumbent wins ties.
#define INS3(d, idx, E0, E1, E2, I0, I1, I2) do {                     \
    bool c0 = (d) < E0, c1 = (d) < E1, c2 = (d) < E2;                 \
    float n1_ = __builtin_amdgcn_fmed3f(E0, E1, (d));                 \
    float n2_ = __builtin_amdgcn_fmed3f(E1, E2, (d));                 \
    I2 = c1 ? I1 : (c2 ? (idx) : I2);                                 \
    I1 = c0 ? I0 : (c1 ? (idx) : I1);                                 \
    I0 = c0 ? (idx) : I0;                                             \
    E0 = fminf(E0, (d)); E1 = n1_; E2 = n2_;                          \
} while (0)

// shared IDW epilogue: id* are global sorted candidate indices
__device__ __forceinline__ void idw_write(
    float qx, float qy, float qz, int n0, int n1, int n2,
    const float4* __restrict__ ckey, const float4* __restrict__ cflow,
    float* __restrict__ out, int b, int origj)
{
    float wsum = 0.f, f2x = 0.f, f2y = 0.f, f2z = 0.f;
    int idxs[3] = { n0, n1, n2 };
    #pragma unroll
    for (int k = 0; k < 3; ++k) {
        int id = idxs[k];
        float4 c = ckey[id];
        float cx = -0.5f * c.x, cy = -0.5f * c.y, cz = -0.5f * c.z;  // exact
        float dx = cx - qx, dy = cy - qy, dz = cz - qz;
        float dist = sqrtf(fmaf(dx, dx, fmaf(dy, dy, dz * dz)));
        dist = fmaxf(dist, 1e-10f);
        float w = 1.0f / dist;
        wsum += w;
        float4 fl = cflow[id];
        f2x = fmaf(w, fl.x, f2x);
        f2y = fmaf(w, fl.y, f2y);
        f2z = fmaf(w, fl.z, f2z);
    }
    float r = 1.0f / wsum;
    float* ob = out + b * 3 * NPTS;
    ob[origj]            = qx - f2x * r;
    ob[NPTS + origj]     = qy - f2y * r;
    ob[2 * NPTS + origj] = qz - f2z * r;
}

// ---------------------------------------------------------------------------
// K1: histogram candidates AND queries on the same padded grid.
// ---------------------------------------------------------------------------
__global__ __launch_bounds__(256) void bin_both(
    const float* __restrict__ xyz1, const float* __restrict__ xyz2,
    const float* __restrict__ flow1, int* __restrict__ counts_c,
    int* __restrict__ counts_q)
{
    int t = blockIdx.x * 256 + threadIdx.x;       // 2*BATCH*NPTS threads
    if (t < BATCH * NPTS) {
        int b = t >> 13, n = t & (NPTS - 1);
        const float* x = xyz1 + b * 3 * NPTS + n;
        const float* f = flow1 + b * 3 * NPTS + n;
        float wx = x[0] + f[0], wy = x[NPTS] + f[NPTS], wz = x[2*NPTS] + f[2*NPTS];
        int loc = (cellc(wz) * GS + cellc(wy)) * GS + cellc(wx);
        atomicAdd(&counts_c[b * NCP + loc], 1);
    } else {
        int tq = t - BATCH * NPTS;
        int b = tq >> 13, n = tq & (NPTS - 1);
        const float* q = xyz2 + b * 3 * NPTS + n;
        int loc = (cellc(q[2*NPTS]) * GS + cellc(q[NPTS])) * GS + cellc(q[0]);
        atomicAdd(&counts_q[b * NCP + loc], 1);
    }
}

// ---------------------------------------------------------------------------
// K2: exclusive prefix scan, 8 blocks: 0-3 candidate cells, 4-7 query cells.
// NCP=16384 = 4 chunks of 4096 (int4/thread), Hillis-Steele over 1024 sums.
// ---------------------------------------------------------------------------
__global__ __launch_bounds__(1024) void scan_chunks(
    const int* __restrict__ cc, int* __restrict__ cs, int* __restrict__ ccur,
    const int* __restrict__ qc, int* __restrict__ qs, int* __restrict__ qcur)
{
    __shared__ int part[1024];
    int blk = blockIdx.x, t = (int)threadIdx.x;
    const int* cnts; int* oS; int* oC; int batch;
    if (blk < 4) { batch = blk;     cnts = cc; oS = cs; oC = ccur; }
    else         { batch = blk - 4; cnts = qc; oS = qs; oC = qcur; }

    int base = batch * NCP;
    int carry = batch * NPTS;
    for (int ch = 0; ch < NCP; ch += 4096) {
        int4 v = *(const int4*)&cnts[base + ch + t * 4];
        part[t] = v.x + v.y + v.z + v.w;
        __syncthreads();
        for (int off = 1; off < 1024; off <<= 1) {
            int pv = (t >= off) ? part[t - off] : 0;
            __syncthreads();
            part[t] += pv;
            __syncthreads();
        }
        int excl = carry + ((t > 0) ? part[t - 1] : 0);
        int4 o; o.x = excl; o.y = excl + v.x; o.z = o.y + v.y; o.w = o.z + v.z;
        *(int4*)&oS[base + ch + t * 4] = o;
        *(int4*)&oC[base + ch + t * 4] = o;
        carry += part[1023];
        __syncthreads();
    }
    if (t == 1023) oS[base + NCP] = carry;   // sentinel (benign dup for b<3)
}

// ---------------------------------------------------------------------------
// K3: scatter candidates into cell-sorted order (key + flow).
// ---------------------------------------------------------------------------
__global__ __launch_bounds__(256) void scatter_c(
    const float* __restrict__ xyz1, const float* __restrict__ flow1,
    int* __restrict__ ccur, float4* __restrict__ ckey, float4* __restrict__ cflow)
{
    int t = blockIdx.x * 256 + threadIdx.x;
    int b = t >> 13, n = t & (NPTS - 1);
    const float* x = xyz1 + b * 3 * NPTS + n;
    const float* f = flow1 + b * 3 * NPTS + n;
    float fx = f[0], fy = f[NPTS], fz = f[2*NPTS];
    float wx = x[0] + fx, wy = x[NPTS] + fy, wz = x[2*NPTS] + fz;
    float nrm = fmaf(wx, wx, fmaf(wy, wy, wz * wz));
    int loc = (cellc(wz) * GS + cellc(wy)) * GS + cellc(wx);
    int pos = atomicAdd(&ccur[b * NCP + loc], 1);
    ckey[pos]  = make_float4(-2.0f*wx, -2.0f*wy, -2.0f*wz, nrm);
    cflow[pos] = make_float4(fx, fy, fz, 0.0f);
}

// ---------------------------------------------------------------------------
// K4: scatter queries into cell-sorted order (coords + original index).
// ---------------------------------------------------------------------------
__global__ __launch_bounds__(256) void scatter_q(
    const float* __restrict__ xyz2, int* __restrict__ qcur,
    float4* __restrict__ qpos)
{
    int t = blockIdx.x * 256 + threadIdx.x;
    int b = t >> 13, n = t & (NPTS - 1);
    const float* q = xyz2 + b * 3 * NPTS + n;
    float qx = q[0], qy = q[NPTS], qz = q[2*NPTS];
    int loc = (cellc(qz) * GS + cellc(qy)) * GS + cellc(qx);
    int pos = atomicAdd(&qcur[b * NCP + loc], 1);
    qpos[pos] = make_float4(qx, qy, qz, __int_as_float(n));
}

// ---------------------------------------------------------------------------
// K5: main pass. Block = 512 thr = 64 sorted queries x 8 segments.
// Tile bbox (wave shfl reduce; identical across waves) + 1-cell margin ->
// cell box; its contiguous x-runs are staged chunk-wise into LDS
// (cooperative coalesced loads), then scanned via LDS broadcast: thread
// (q=t&63, s=t>>6) evaluates chunk slots i = s, s+8, ... (wave-uniform addr).
// Per-query exact face margin mg (>= 0.5); resolved iff d3^2 <= mg^2 ->
// IDW output; else append to per-batch compacted fallback list.
// ---------------------------------------------------------------------------
__global__ __launch_bounds__(512, 2) void knn_tile(
    const float4* __restrict__ qpos, const float4* __restrict__ ckey,
    const float4* __restrict__ cflow, const int* __restrict__ cstart,
    int* __restrict__ fbcnt, int* __restrict__ fblist, float* __restrict__ out)
{
    __shared__ float4 sc[CHN];
    __shared__ float  md[NSEG][64][3];
    __shared__ int    mi[NSEG][64][3];

    int tile = blockIdx.x;               // BATCH*128
    int b = tile >> 7, ti = tile & 127;
    int t = (int)threadIdx.x;
    int l = t & 63, s = t >> 6;
    int qbase = b * NPTS + ti * 64;

    float4 qp = qpos[qbase + l];
    float qx = qp.x, qy = qp.y, qz = qp.z;
    int origj = __float_as_int(qp.w);
    float qn = fmaf(qx, qx, fmaf(qy, qy, qz * qz));

    float bxl=qx, bxh=qx, byl=qy, byh=qy, bzl=qz, bzh=qz;
    #pragma unroll
    for (int o = 32; o >= 1; o >>= 1) {
        bxl = fminf(bxl, __shfl_xor(bxl, o));  bxh = fmaxf(bxh, __shfl_xor(bxh, o));
        byl = fminf(byl, __shfl_xor(byl, o));  byh = fmaxf(byh, __shfl_xor(byh, o));
        bzl = fminf(bzl, __shfl_xor(bzl, o));  bzh = fmaxf(bzh, __shfl_xor(bzh, o));
    }
    int lox = max(cellc(bxl) - 1, 0), hix = min(cellc(bxh) + 1, GS - 1);
    int loy = max(cellc(byl) - 1, 0), hiy = min(cellc(byh) + 1, GS - 1);
    int loz = max(cellc(bzl) - 1, 0), hiz = min(cellc(bzh) + 1, GS - 1);

    float e0 = FINF, e1 = FINF, e2 = FINF;
    int   i0 = 0, i1 = 0, i2 = 0;

    for (int z = loz; z <= hiz; ++z)
    for (int y = loy; y <= hiy; ++y) {
        int rbase = b * NCP + (z * GS + y) * GS;
        int st = cstart[rbase + lox];
        int en = cstart[rbase + hix + 1];
        for (int k0 = st; k0 < en; k0 += CHN) {
            int C = min(CHN, en - k0);
            __syncthreads();                     // prev chunk fully consumed
            if (t < C) sc[t] = ckey[k0 + t];     // coalesced staging
            __syncthreads();
            for (int i = s; i < C; i += NSEG) {  // wave-uniform LDS broadcast
                float4 c = sc[i];
                float d = fmaf(c.x, qx, fmaf(c.y, qy, fmaf(c.z, qz, c.w)));
                int kk = k0 + i;
                INS3(d, kk, e0, e1, e2, i0, i1, i2);
            }
        }
    }

    md[s][l][0] = e0; md[s][l][1] = e1; md[s][l][2] = e2;
    mi[s][l][0] = i0; mi[s][l][1] = i1; mi[s][l][2] = i2;
    __syncthreads();

    if (t < 64) {
        float m0 = FINF, m1 = FINF, m2 = FINF;
        int   n0 = 0, n1 = 0, n2 = 0;
        #pragma unroll
        for (int ss = 0; ss < NSEG; ++ss) {
            INS3(md[ss][t][0], mi[ss][t][0], m0, m1, m2, n0, n1, n2);
            INS3(md[ss][t][1], mi[ss][t][1], m0, m1, m2, n0, n1, n2);
            INS3(md[ss][t][2], mi[ss][t][2], m0, m1, m2, n0, n1, n2);
        }
        // exact per-query margin to box faces (grid-edge faces unbounded)
        float mg = FINF;
        if (lox > 0)      mg = fminf(mg, qx - (GMIN + lox * CS));
        if (hix < GS - 1) mg = fminf(mg, (GMIN + (hix + 1) * CS) - qx);
        if (loy > 0)      mg = fminf(mg, qy - (GMIN + loy * CS));
        if (hiy < GS - 1) mg = fminf(mg, (GMIN + (hiy + 1) * CS) - qy);
        if (loz > 0)      mg = fminf(mg, qz - (GMIN + loz * CS));
        if (hiz < GS - 1) mg = fminf(mg, (GMIN + (hiz + 1) * CS) - qz);
        if (m2 + qn <= mg * mg) {
            idw_write(qx, qy, qz, n0, n1, n2, ckey, cflow, out, b, origj);
        } else {
            int p = atomicAdd(&fbcnt[b], 1);
            fblist[b * NPTS + p] = ti * 64 + t;  // batch-local sorted position
        }
    }
}

// ---------------------------------------------------------------------------
// K6: fallback segmented brute scan (R7 structure) over compacted queries.
// blk -> (b, grp, seg); batch-uniform candidate stream (scalarizable).
// Blocks past the count exit immediately.
// ---------------------------------------------------------------------------
__global__ __launch_bounds__(256) void fb_scan(
    const float4* __restrict__ qpos, const float4* __restrict__ ckey,
    const int* __restrict__ fbcnt, const int* __restrict__ fblist,
    float* __restrict__ pd, unsigned short* __restrict__ pi)
{
    int blk = blockIdx.x;                 // 4*32*8 = 1024
    int seg = blk & 7, grp = (blk >> 3) & 31, b = blk >> 8;
    int t = (int)threadIdx.x;
    int cnt = fbcnt[b];
    if (grp * 256 >= cnt) return;
    int idx = grp * 256 + t;
    bool act = idx < cnt;
    int js = fblist[b * NPTS + (act ? idx : 0)];
    float4 qp = qpos[b * NPTS + js];
    float qx = qp.x, qy = qp.y, qz = qp.z;

    const float4* src = ckey + b * NPTS + seg * FSEGLEN;   // block-uniform

    float e0 = FINF, e1 = FINF, e2 = FINF;
    int   i0 = 0, i1 = 0, i2 = 0;
    #pragma unroll 8
    for (int k = 0; k < FSEGLEN; ++k) {
        float4 c = src[k];
        float d = fmaf(c.x, qx, fmaf(c.y, qy, fmaf(c.z, qz, c.w)));
        INS3(d, k, e0, e1, e2, i0, i1, i2);
    }
    if (act) {
        int off = seg * FSEGLEN;
        size_t base = ((size_t)(b * NPTS + idx) * NSEG + seg) * 3;
        pd[base]   = e0;  pi[base]   = (unsigned short)(i0 + off);
        pd[base+1] = e1;  pi[base+1] = (unsigned short)(i1 + off);
        pd[base+2] = e2;  pi[base+2] = (unsigned short)(i2 + off);
    }
}

// ---------------------------------------------------------------------------
// K7: fallback merge + IDW epilogue for compacted queries.
// ---------------------------------------------------------------------------
__global__ __launch_bounds__(256) void fb_merge(
    const float4* __restrict__ qpos, const float4* __restrict__ ckey,
    const float4* __restrict__ cflow, const int* __restrict__ fbcnt,
    const int* __restrict__ fblist, const float* __restrict__ pd,
    const unsigned short* __restrict__ pi, float* __restrict__ out)
{
    int blk = blockIdx.x;                 // 4*32 = 128
    int grp = blk & 31, b = blk >> 5;
    int t = (int)threadIdx.x;
    int cnt = fbcnt[b];
    if (grp * 256 >= cnt) return;
    int idx = grp * 256 + t;
    if (idx >= cnt) return;
    int js = fblist[b * NPTS + idx];
    float4 qp = qpos[b * NPTS + js];
    float qx = qp.x, qy = qp.y, qz = qp.z;
    int origj = __float_as_int(qp.w);

    float m0 = FINF, m1 = FINF, m2 = FINF;
    int   n0 = 0, n1 = 0, n2 = 0;
    #pragma unroll
    for (int s = 0; s < NSEG; ++s) {
        size_t base = ((size_t)(b * NPTS + idx) * NSEG + s) * 3;
        INS3(pd[base],   (int)pi[base],   m0, m1, m2, n0, n1, n2);
        INS3(pd[base+1], (int)pi[base+1], m0, m1, m2, n0, n1, n2);
        INS3(pd[base+2], (int)pi[base+2], m0, m1, m2, n0, n1, n2);
    }
    idw_write(qx, qy, qz, b * NPTS + n0, b * NPTS + n1, b * NPTS + n2,
              ckey, cflow, out, b, origj);
}

// ---------------------------------------------------------------------------
// Launcher. Workspace ~7.6 MB (< 9.95 MB proven in R7):
// ckey 512K | cflow 512K | qpos 512K | [counts_c 256K | counts_q 256K |
// fbcnt 16B] (zeroed) | cstart 256K+ | ccur 256K | qstart 256K+ | qcur 256K |
// fblist 128K | pd 3M | pi 1.5M
// ---------------------------------------------------------------------------
extern "C" void kernel_launch(void* const* d_in, const int* in_sizes, int n_in,
                              void* d_out, int out_size, void* d_ws, size_t ws_size,
                              hipStream_t stream)
{
    const float* xyz1  = (const float*)d_in[0];
    const float* xyz2  = (const float*)d_in[1];
    const float* flow1 = (const float*)d_in[2];
    float* out = (float*)d_out;

    char* p = (char*)d_ws;
    float4* ckey     = (float4*)p;  p += (size_t)BATCH * NPTS * 16;
    float4* cflow    = (float4*)p;  p += (size_t)BATCH * NPTS * 16;
    float4* qpos     = (float4*)p;  p += (size_t)BATCH * NPTS * 16;
    int*    counts_c = (int*)p;     p += (size_t)BATCH * NCP * 4;
    int*    counts_q = (int*)p;     p += (size_t)BATCH * NCP * 4;
    int*    fbcnt    = (int*)p;     p += 16;
    int*    cstart   = (int*)p;     p += ((size_t)BATCH * NCP + 4) * 4;
    int*    ccur     = (int*)p;     p += (size_t)BATCH * NCP * 4;
    int*    qstart   = (int*)p;     p += ((size_t)BATCH * NCP + 4) * 4;
    int*    qcur     = (int*)p;     p += (size_t)BATCH * NCP * 4;
    int*    fblist   = (int*)p;     p += (size_t)BATCH * NPTS * 4;
    float*  pd       = (float*)p;   p += (size_t)BATCH * NPTS * NSEG * 3 * 4;
    unsigned short* pi = (unsigned short*)p;

    // zero counts_c + counts_q + fbcnt in one shot (contiguous)
    hipMemsetAsync(counts_c, 0, (size_t)BATCH * NCP * 4 * 2 + 16, stream);
    bin_both   <<<2 * BATCH * NPTS / 256, 256, 0, stream>>>(xyz1, xyz2, flow1, counts_c, counts_q);
    scan_chunks<<<8, 1024, 0, stream>>>(counts_c, cstart, ccur, counts_q, qstart, qcur);
    scatter_c  <<<BATCH * NPTS / 256, 256, 0, stream>>>(xyz1, flow1, ccur, ckey, cflow);
    scatter_q  <<<BATCH * NPTS / 256, 256, 0, stream>>>(xyz2, qcur, qpos);
    knn_tile   <<<BATCH * (NPTS / 64), 512, 0, stream>>>(qpos, ckey, cflow, cstart, fbcnt, fblist, out);
    fb_scan    <<<BATCH * 32 * NSEG, 256, 0, stream>>>(qpos, ckey, fbcnt, fblist, pd, pi);
    fb_merge   <<<BATCH * 32, 256, 0, stream>>>(qpos, ckey, cflow, fbcnt, fblist, pd, pi, out);
}

// Round 11
// 193.618 us; speedup vs baseline: 33.3271x; 1.3466x over previous
//
#include <hip/hip_runtime.h>
#include <math.h>

#define BATCH 4
#define NPTS 8192
#define GS 24                  // 24^3 cells of 0.5 over [-6,6]^3
#define NCP 16384              // padded cells per batch (24^3 = 13824)
#define GMIN (-6.0f)
#define CS 0.5f
#define INVCS 2.0f
#define FINF 3.4e38f
#define QPT 32                 // queries per tile
#define BUF 1536               // LDS staging slots (float4 + int idx)
#define NSEG 8                 // fallback segments
#define FSEGLEN (NPTS / NSEG)  // 1024

__device__ __forceinline__ int cellc(float v) {
    int c = (int)((v - GMIN) * INVCS);
    return min(max(c, 0), GS - 1);
}

// branchless sorted top-3 update (R5-proven). Strict '<': incumbent wins ties.
#define INS3(d, idx, E0, E1, E2, I0, I1, I2) do {                     \
    bool c0 = (d) < E0, c1 = (d) < E1, c2 = (d) < E2;                 \
    float n1_ = __builtin_amdgcn_fmed3f(E0, E1, (d));                 \
    float n2_ = __builtin_amdgcn_fmed3f(E1, E2, (d));                 \
    I2 = c1 ? I1 : (c2 ? (idx) : I2);                                 \
    I1 = c0 ? I0 : (c1 ? (idx) : I1);                                 \
    I0 = c0 ? (idx) : I0;                                             \
    E0 = fminf(E0, (d)); E1 = n1_; E2 = n2_;                          \
} while (0)

// shared IDW epilogue: id* are global sorted candidate indices
__device__ __forceinline__ void idw_write(
    float qx, float qy, float qz, int n0, int n1, int n2,
    const float4* __restrict__ ckey, const float4* __restrict__ cflow,
    float* __restrict__ out, int b, int origj)
{
    float wsum = 0.f, f2x = 0.f, f2y = 0.f, f2z = 0.f;
    int idxs[3] = { n0, n1, n2 };
    #pragma unroll
    for (int k = 0; k < 3; ++k) {
        int id = idxs[k];
        float4 c = ckey[id];
        float cx = -0.5f * c.x, cy = -0.5f * c.y, cz = -0.5f * c.z;  // exact
        float dx = cx - qx, dy = cy - qy, dz = cz - qz;
        float dist = sqrtf(fmaf(dx, dx, fmaf(dy, dy, dz * dz)));
        dist = fmaxf(dist, 1e-10f);
        float w = 1.0f / dist;
        wsum += w;
        float4 fl = cflow[id];
        f2x = fmaf(w, fl.x, f2x);
        f2y = fmaf(w, fl.y, f2y);
        f2z = fmaf(w, fl.z, f2z);
    }
    float r = 1.0f / wsum;
    float* ob = out + b * 3 * NPTS;
    ob[origj]            = qx - f2x * r;
    ob[NPTS + origj]     = qy - f2y * r;
    ob[2 * NPTS + origj] = qz - f2z * r;
}

// ---------------------------------------------------------------------------
// K1: histogram candidates AND queries on the same padded grid.
// ---------------------------------------------------------------------------
__global__ __launch_bounds__(256) void bin_both(
    const float* __restrict__ xyz1, const float* __restrict__ xyz2,
    const float* __restrict__ flow1, int* __restrict__ counts_c,
    int* __restrict__ counts_q)
{
    int t = blockIdx.x * 256 + threadIdx.x;       // 2*BATCH*NPTS threads
    if (t < BATCH * NPTS) {
        int b = t >> 13, n = t & (NPTS - 1);
        const float* x = xyz1 + b * 3 * NPTS + n;
        const float* f = flow1 + b * 3 * NPTS + n;
        float wx = x[0] + f[0], wy = x[NPTS] + f[NPTS], wz = x[2*NPTS] + f[2*NPTS];
        int loc = (cellc(wz) * GS + cellc(wy)) * GS + cellc(wx);
        atomicAdd(&counts_c[b * NCP + loc], 1);
    } else {
        int tq = t - BATCH * NPTS;
        int b = tq >> 13, n = tq & (NPTS - 1);
        const float* q = xyz2 + b * 3 * NPTS + n;
        int loc = (cellc(q[2*NPTS]) * GS + cellc(q[NPTS])) * GS + cellc(q[0]);
        atomicAdd(&counts_q[b * NCP + loc], 1);
    }
}

// ---------------------------------------------------------------------------
// K2: exclusive prefix scan via shfl (3 barriers/chunk vs 20 for H-S).
// 8 blocks: 0-3 candidate cells, 4-7 query cells; 4 chunks of 4096 each.
// ---------------------------------------------------------------------------
__global__ __launch_bounds__(1024) void scan_chunks(
    const int* __restrict__ cc, int* __restrict__ cs, int* __restrict__ ccur,
    const int* __restrict__ qc, int* __restrict__ qs, int* __restrict__ qcur)
{
    __shared__ int wsum[16];
    __shared__ int wpre[16];
    __shared__ int ctot;
    int blk = blockIdx.x, t = (int)threadIdx.x;
    int lane = t & 63, wid = t >> 6;
    const int* cnts; int* oS; int* oC; int batch;
    if (blk < 4) { batch = blk;     cnts = cc; oS = cs; oC = ccur; }
    else         { batch = blk - 4; cnts = qc; oS = qs; oC = qcur; }
    int base = batch * NCP;
    int carry = batch * NPTS;
    for (int ch = 0; ch < NCP; ch += 4096) {
        int4 v = *(const int4*)&cnts[base + ch + t * 4];
        int tsum = v.x + v.y + v.z + v.w;
        int incl = tsum;
        #pragma unroll
        for (int o = 1; o < 64; o <<= 1) {
            int n = __shfl_up(incl, o);
            if (lane >= o) incl += n;
        }
        if (lane == 63) wsum[wid] = incl;
        __syncthreads();
        if (t < 16) {
            int wv = wsum[t];
            int wincl = wv;
            #pragma unroll
            for (int o = 1; o < 16; o <<= 1) {
                int n = __shfl_up(wincl, o);
                if (t >= o) wincl += n;
            }
            wpre[t] = wincl - wv;
            if (t == 15) ctot = wincl;
        }
        __syncthreads();
        int excl = carry + wpre[wid] + (incl - tsum);
        int4 o4; o4.x = excl; o4.y = excl + v.x; o4.z = o4.y + v.y; o4.w = o4.z + v.z;
        *(int4*)&oS[base + ch + t * 4] = o4;
        *(int4*)&oC[base + ch + t * 4] = o4;
        carry += ctot;
        __syncthreads();
    }
    if (t == 0) oS[base + NCP] = carry;   // sentinel
}

// ---------------------------------------------------------------------------
// K3: scatter candidates into cell-sorted order (key + flow).
// ---------------------------------------------------------------------------
__global__ __launch_bounds__(256) void scatter_c(
    const float* __restrict__ xyz1, const float* __restrict__ flow1,
    int* __restrict__ ccur, float4* __restrict__ ckey, float4* __restrict__ cflow)
{
    int t = blockIdx.x * 256 + threadIdx.x;
    int b = t >> 13, n = t & (NPTS - 1);
    const float* x = xyz1 + b * 3 * NPTS + n;
    const float* f = flow1 + b * 3 * NPTS + n;
    float fx = f[0], fy = f[NPTS], fz = f[2*NPTS];
    float wx = x[0] + fx, wy = x[NPTS] + fy, wz = x[2*NPTS] + fz;
    float nrm = fmaf(wx, wx, fmaf(wy, wy, wz * wz));
    int loc = (cellc(wz) * GS + cellc(wy)) * GS + cellc(wx);
    int pos = atomicAdd(&ccur[b * NCP + loc], 1);
    ckey[pos]  = make_float4(-2.0f*wx, -2.0f*wy, -2.0f*wz, nrm);
    cflow[pos] = make_float4(fx, fy, fz, 0.0f);
}

// ---------------------------------------------------------------------------
// K4: scatter queries into cell-sorted order (coords + original index).
// ---------------------------------------------------------------------------
__global__ __launch_bounds__(256) void scatter_q(
    const float* __restrict__ xyz2, int* __restrict__ qcur,
    float4* __restrict__ qpos)
{
    int t = blockIdx.x * 256 + threadIdx.x;
    int b = t >> 13, n = t & (NPTS - 1);
    const float* q = xyz2 + b * 3 * NPTS + n;
    float qx = q[0], qy = q[NPTS], qz = q[2*NPTS];
    int loc = (cellc(qz) * GS + cellc(qy)) * GS + cellc(qx);
    int pos = atomicAdd(&qcur[b * NCP + loc], 1);
    qpos[pos] = make_float4(qx, qy, qz, __int_as_float(n));
}

// ---------------------------------------------------------------------------
// K5: main pass, accumulate-then-stream.
// Block = 256 thr = 32 sorted queries (lane l = query t&31) x 8 slot-streams
// (so = t>>5). Per z-slab: active queries (|hz-z|<=1) define a tight y/x
// window; per-row [st,len) + offsets via a 64-lane shfl scan (registers, no
// barriers); rows copied cooperatively (wave w takes rows w,w+4,..) into a
// 1536-slot LDS buffer that accumulates ACROSS slabs and is streamed in one
// long broadcast pass when full / at the end. ~4 barriers per tile.
// Resolve: per-query +-1-cell-box margin mg (faces at grid edge skipped):
// unscanned points lie outside the query's +-1 box => dist >= mg. Exact.
// ---------------------------------------------------------------------------
#define STREAM(lim) do {                                              \
    for (int i_ = so; i_ < (lim); i_ += 8) {                          \
        float4 c_ = sc[i_];                                           \
        int kk_ = sidx[i_];                                           \
        float d_ = fmaf(c_.x, qx, fmaf(c_.y, qy, fmaf(c_.z, qz, c_.w))); \
        INS3(d_, kk_, e0, e1, e2, i0, i1, i2);                        \
    }                                                                 \
} while (0)

__global__ __launch_bounds__(256) void knn_tile(
    const float4* __restrict__ qpos, const float4* __restrict__ ckey,
    const float4* __restrict__ cflow, const int* __restrict__ cstart,
    int* __restrict__ fbcnt, int* __restrict__ fblist, float* __restrict__ out)
{
    __shared__ float4 sc[BUF];
    __shared__ int    sidx[BUF];
    float* md = (float*)&sc[0];                       // [8][32][3], aliases sc
    int*   mi = (int*)((char*)&sc[0] + 3072);         // (used only after final stream)

    int tile = blockIdx.x;               // BATCH*256
    int b = tile >> 8, ti = tile & 255;
    int t = (int)threadIdx.x;
    int lane = t & 63, so = t >> 5, l = t & 31, w = t >> 6;
    int qbase = b * NPTS + ti * QPT;

    float4 qp = qpos[qbase + l];
    float qx = qp.x, qy = qp.y, qz = qp.z;
    int origj = __float_as_int(qp.w);
    float qn = fmaf(qx, qx, fmaf(qy, qy, qz * qz));
    int hx = cellc(qx), hy = cellc(qy), hz = cellc(qz);

    int zmn = hz, zmx = hz;
    #pragma unroll
    for (int o = 32; o >= 1; o >>= 1) {
        zmn = min(zmn, __shfl_xor(zmn, o));
        zmx = max(zmx, __shfl_xor(zmx, o));
    }
    int loz = max(zmn - 1, 0), hiz = min(zmx + 1, GS - 1);

    float e0 = FINF, e1 = FINF, e2 = FINF;
    int   i0 = 0, i1 = 0, i2 = 0;
    int bufofs = 0;
    int bN = b * NCP;

    for (int z = loz; z <= hiz; ++z) {
        bool act = (hz - z <= 1) && (z - hz <= 1);
        int ymn = act ? hy : 1000, ymx = act ? hy : -1000;
        int xmn = act ? hx : 1000, xmx = act ? hx : -1000;
        #pragma unroll
        for (int o = 32; o >= 1; o >>= 1) {
            ymn = min(ymn, __shfl_xor(ymn, o));
            ymx = max(ymx, __shfl_xor(ymx, o));
            xmn = min(xmn, __shfl_xor(xmn, o));
            xmx = max(xmx, __shfl_xor(xmx, o));
        }
        if (ymn == 1000) continue;                 // no query needs this slab
        int ylo = max(ymn - 1, 0), yhi = min(ymx + 1, GS - 1);
        int xlo = max(xmn - 1, 0), xhi = min(xmx + 1, GS - 1);
        int nrows = yhi - ylo + 1;                 // <= 24 < 64

        int strt = 0, rlen = 0;
        if (lane < nrows) {
            int rb = bN + (z * GS + (ylo + lane)) * GS;
            strt = cstart[rb + xlo];
            rlen = cstart[rb + xhi + 1] - strt;
        }
        int incl = rlen;
        #pragma unroll
        for (int o = 1; o < 64; o <<= 1) {
            int n = __shfl_up(incl, o);
            if (lane >= o) incl += n;
        }
        int excl = incl - rlen;
        int T = __shfl(incl, 63);

        int copied = 0;
        while (copied < T) {                       // uniform loop
            int cnt = min(T - copied, BUF - bufofs);
            for (int r = w; r < nrows; r += 4) {   // wave w copies rows w,w+4,..
                int rofs = __shfl(excl, r);
                int rst  = __shfl(strt, r);
                int rln  = __shfl(rlen, r);
                int lo = max(rofs, copied), hi = min(rofs + rln, copied + cnt);
                for (int i = lo + lane; i < hi; i += 64) {
                    int dst = bufofs + (i - copied);
                    int src = rst + (i - rofs);
                    sc[dst] = ckey[src];
                    sidx[dst] = src;
                }
            }
            bufofs += cnt; copied += cnt;
            if (bufofs == BUF) {                   // uniform
                __syncthreads();
                STREAM(BUF);
                __syncthreads();
                bufofs = 0;
            }
        }
    }
    __syncthreads();
    if (bufofs > 0) STREAM(bufofs);                // uniform
    __syncthreads();                               // sc reuse as md/mi below

    md[(so * 32 + l) * 3 + 0] = e0;  mi[(so * 32 + l) * 3 + 0] = i0;
    md[(so * 32 + l) * 3 + 1] = e1;  mi[(so * 32 + l) * 3 + 1] = i1;
    md[(so * 32 + l) * 3 + 2] = e2;  mi[(so * 32 + l) * 3 + 2] = i2;
    __syncthreads();

    if (t < 32) {
        float m0 = FINF, m1 = FINF, m2 = FINF;
        int   n0 = 0, n1 = 0, n2 = 0;
        #pragma unroll
        for (int ss = 0; ss < 8; ++ss) {
            int bx = (ss * 32 + t) * 3;
            INS3(md[bx],     mi[bx],     m0, m1, m2, n0, n1, n2);
            INS3(md[bx + 1], mi[bx + 1], m0, m1, m2, n0, n1, n2);
            INS3(md[bx + 2], mi[bx + 2], m0, m1, m2, n0, n1, n2);
        }
        // per-query margin: distance to own +-1-cell-box faces (grid-edge skipped)
        float mg = FINF;
        if (hx > 1)      mg = fminf(mg, qx - (GMIN + (hx - 1) * CS));
        if (hx < GS - 2) mg = fminf(mg, (GMIN + (hx + 2) * CS) - qx);
        if (hy > 1)      mg = fminf(mg, qy - (GMIN + (hy - 1) * CS));
        if (hy < GS - 2) mg = fminf(mg, (GMIN + (hy + 2) * CS) - qy);
        if (hz > 1)      mg = fminf(mg, qz - (GMIN + (hz - 1) * CS));
        if (hz < GS - 2) mg = fminf(mg, (GMIN + (hz + 2) * CS) - qz);
        if (m2 + qn <= mg * mg) {
            idw_write(qx, qy, qz, n0, n1, n2, ckey, cflow, out, b, origj);
        } else {
            int p = atomicAdd(&fbcnt[b], 1);
            fblist[b * NPTS + p] = ti * QPT + t;   // batch-local sorted position
        }
    }
}

// ---------------------------------------------------------------------------
// K6: fallback segmented brute scan (R7 structure) over compacted queries.
// ---------------------------------------------------------------------------
__global__ __launch_bounds__(256) void fb_scan(
    const float4* __restrict__ qpos, const float4* __restrict__ ckey,
    const int* __restrict__ fbcnt, const int* __restrict__ fblist,
    float* __restrict__ pd, unsigned short* __restrict__ pi)
{
    int blk = blockIdx.x;                 // 4*32*8 = 1024
    int seg = blk & 7, grp = (blk >> 3) & 31, b = blk >> 8;
    int t = (int)threadIdx.x;
    int cnt = fbcnt[b];
    if (grp * 256 >= cnt) return;
    int idx = grp * 256 + t;
    bool act = idx < cnt;
    int js = fblist[b * NPTS + (act ? idx : 0)];
    float4 qp = qpos[b * NPTS + js];
    float qx = qp.x, qy = qp.y, qz = qp.z;

    const float4* src = ckey + b * NPTS + seg * FSEGLEN;   // block-uniform

    float e0 = FINF, e1 = FINF, e2 = FINF;
    int   i0 = 0, i1 = 0, i2 = 0;
    #pragma unroll 8
    for (int k = 0; k < FSEGLEN; ++k) {
        float4 c = src[k];
        float d = fmaf(c.x, qx, fmaf(c.y, qy, fmaf(c.z, qz, c.w)));
        INS3(d, k, e0, e1, e2, i0, i1, i2);
    }
    if (act) {
        int off = seg * FSEGLEN;
        size_t base = ((size_t)(b * NPTS + idx) * NSEG + seg) * 3;
        pd[base]   = e0;  pi[base]   = (unsigned short)(i0 + off);
        pd[base+1] = e1;  pi[base+1] = (unsigned short)(i1 + off);
        pd[base+2] = e2;  pi[base+2] = (unsigned short)(i2 + off);
    }
}

// ---------------------------------------------------------------------------
// K7: fallback merge + IDW epilogue.
// ---------------------------------------------------------------------------
__global__ __launch_bounds__(256) void fb_merge(
    const float4* __restrict__ qpos, const float4* __restrict__ ckey,
    const float4* __restrict__ cflow, const int* __restrict__ fbcnt,
    const int* __restrict__ fblist, const float* __restrict__ pd,
    const unsigned short* __restrict__ pi, float* __restrict__ out)
{
    int blk = blockIdx.x;                 // 4*32 = 128
    int grp = blk & 31, b = blk >> 5;
    int t = (int)threadIdx.x;
    int cnt = fbcnt[b];
    if (grp * 256 >= cnt) return;
    int idx = grp * 256 + t;
    if (idx >= cnt) return;
    int js = fblist[b * NPTS + idx];
    float4 qp = qpos[b * NPTS + js];
    float qx = qp.x, qy = qp.y, qz = qp.z;
    int origj = __float_as_int(qp.w);

    float m0 = FINF, m1 = FINF, m2 = FINF;
    int   n0 = 0, n1 = 0, n2 = 0;
    #pragma unroll
    for (int s = 0; s < NSEG; ++s) {
        size_t base = ((size_t)(b * NPTS + idx) * NSEG + s) * 3;
        INS3(pd[base],   (int)pi[base],   m0, m1, m2, n0, n1, n2);
        INS3(pd[base+1], (int)pi[base+1], m0, m1, m2, n0, n1, n2);
        INS3(pd[base+2], (int)pi[base+2], m0, m1, m2, n0, n1, n2);
    }
    idw_write(qx, qy, qz, b * NPTS + n0, b * NPTS + n1, b * NPTS + n2,
              ckey, cflow, out, b, origj);
}

// ---------------------------------------------------------------------------
// Launcher. Workspace ~7.6 MB (fits: R10 ran this exact footprint).
// ---------------------------------------------------------------------------
extern "C" void kernel_launch(void* const* d_in, const int* in_sizes, int n_in,
                              void* d_out, int out_size, void* d_ws, size_t ws_size,
                              hipStream_t stream)
{
    const float* xyz1  = (const float*)d_in[0];
    const float* xyz2  = (const float*)d_in[1];
    const float* flow1 = (const float*)d_in[2];
    float* out = (float*)d_out;

    char* p = (char*)d_ws;
    float4* ckey     = (float4*)p;  p += (size_t)BATCH * NPTS * 16;
    float4* cflow    = (float4*)p;  p += (size_t)BATCH * NPTS * 16;
    float4* qpos     = (float4*)p;  p += (size_t)BATCH * NPTS * 16;
    int*    counts_c = (int*)p;     p += (size_t)BATCH * NCP * 4;
    int*    counts_q = (int*)p;     p += (size_t)BATCH * NCP * 4;
    int*    fbcnt    = (int*)p;     p += 16;
    int*    cstart   = (int*)p;     p += ((size_t)BATCH * NCP + 4) * 4;
    int*    ccur     = (int*)p;     p += (size_t)BATCH * NCP * 4;
    int*    qstart   = (int*)p;     p += ((size_t)BATCH * NCP + 4) * 4;
    int*    qcur     = (int*)p;     p += (size_t)BATCH * NCP * 4;
    int*    fblist   = (int*)p;     p += (size_t)BATCH * NPTS * 4;
    float*  pd       = (float*)p;   p += (size_t)BATCH * NPTS * NSEG * 3 * 4;
    unsigned short* pi = (unsigned short*)p;

    // zero counts_c + counts_q + fbcnt in one shot (contiguous)
    hipMemsetAsync(counts_c, 0, (size_t)BATCH * NCP * 4 * 2 + 16, stream);
    bin_both   <<<2 * BATCH * NPTS / 256, 256, 0, stream>>>(xyz1, xyz2, flow1, counts_c, counts_q);
    scan_chunks<<<8, 1024, 0, stream>>>(counts_c, cstart, ccur, counts_q, qstart, qcur);
    scatter_c  <<<BATCH * NPTS / 256, 256, 0, stream>>>(xyz1, flow1, ccur, ckey, cflow);
    scatter_q  <<<BATCH * NPTS / 256, 256, 0, stream>>>(xyz2, qcur, qpos);
    knn_tile   <<<BATCH * (NPTS / QPT), 256, 0, stream>>>(qpos, ckey, cflow, cstart, fbcnt, fblist, out);
    fb_scan    <<<BATCH * 32 * NSEG, 256, 0, stream>>>(qpos, ckey, fbcnt, fblist, pd, pi);
    fb_merge   <<<BATCH * 32, 256, 0, stream>>>(qpos, ckey, cflow, fbcnt, fblist, pd, pi, out);
}

// Round 12
// 106.996 us; speedup vs baseline: 60.3079x; 1.8096x over previous
//
#include <hip/hip_runtime.h>
#include <math.h>

#define BATCH 4
#define NPTS 8192
#define GS 24                  // 24^3 cells of 0.5 over [-6,6]^3
#define NCP 16384              // padded cells per batch (24^3 = 13824)
#define GMIN (-6.0f)
#define CS 0.5f
#define INVCS 2.0f
#define FINF 3.4e38f
#define QPT 32                 // queries per tile
#define BUF 1536               // LDS staging slots (float4 + int idx)

__device__ __forceinline__ int cellc(float v) {
    int c = (int)((v - GMIN) * INVCS);
    return min(max(c, 0), GS - 1);
}

// branchless sorted top-3 update (R5-proven). Strict '<': incumbent wins ties.
#define INS3(d, idx, E0, E1, E2, I0, I1, I2) do {                     \
    bool c0 = (d) < E0, c1 = (d) < E1, c2 = (d) < E2;                 \
    float n1_ = __builtin_amdgcn_fmed3f(E0, E1, (d));                 \
    float n2_ = __builtin_amdgcn_fmed3f(E1, E2, (d));                 \
    I2 = c1 ? I1 : (c2 ? (idx) : I2);                                 \
    I1 = c0 ? I0 : (c1 ? (idx) : I1);                                 \
    I0 = c0 ? (idx) : I0;                                             \
    E0 = fminf(E0, (d)); E1 = n1_; E2 = n2_;                          \
} while (0)

// shared IDW epilogue: id* are global sorted candidate indices
__device__ __forceinline__ void idw_write(
    float qx, float qy, float qz, int n0, int n1, int n2,
    const float4* __restrict__ ckey, const float4* __restrict__ cflow,
    float* __restrict__ out, int b, int origj)
{
    float wsum = 0.f, f2x = 0.f, f2y = 0.f, f2z = 0.f;
    int idxs[3] = { n0, n1, n2 };
    #pragma unroll
    for (int k = 0; k < 3; ++k) {
        int id = idxs[k];
        float4 c = ckey[id];
        float cx = -0.5f * c.x, cy = -0.5f * c.y, cz = -0.5f * c.z;  // exact
        float dx = cx - qx, dy = cy - qy, dz = cz - qz;
        float dist = sqrtf(fmaf(dx, dx, fmaf(dy, dy, dz * dz)));
        dist = fmaxf(dist, 1e-10f);
        float w = 1.0f / dist;
        wsum += w;
        float4 fl = cflow[id];
        f2x = fmaf(w, fl.x, f2x);
        f2y = fmaf(w, fl.y, f2y);
        f2z = fmaf(w, fl.z, f2z);
    }
    float r = 1.0f / wsum;
    float* ob = out + b * 3 * NPTS;
    ob[origj]            = qx - f2x * r;
    ob[NPTS + origj]     = qy - f2y * r;
    ob[2 * NPTS + origj] = qz - f2z * r;
}

// ---------------------------------------------------------------------------
// K1: histogram candidates AND queries on the same padded grid.
// ---------------------------------------------------------------------------
__global__ __launch_bounds__(256) void bin_both(
    const float* __restrict__ xyz1, const float* __restrict__ xyz2,
    const float* __restrict__ flow1, int* __restrict__ counts_c,
    int* __restrict__ counts_q)
{
    int t = blockIdx.x * 256 + threadIdx.x;       // 2*BATCH*NPTS threads
    if (t < BATCH * NPTS) {
        int b = t >> 13, n = t & (NPTS - 1);
        const float* x = xyz1 + b * 3 * NPTS + n;
        const float* f = flow1 + b * 3 * NPTS + n;
        float wx = x[0] + f[0], wy = x[NPTS] + f[NPTS], wz = x[2*NPTS] + f[2*NPTS];
        int loc = (cellc(wz) * GS + cellc(wy)) * GS + cellc(wx);
        atomicAdd(&counts_c[b * NCP + loc], 1);
    } else {
        int tq = t - BATCH * NPTS;
        int b = tq >> 13, n = tq & (NPTS - 1);
        const float* q = xyz2 + b * 3 * NPTS + n;
        int loc = (cellc(q[2*NPTS]) * GS + cellc(q[NPTS])) * GS + cellc(q[0]);
        atomicAdd(&counts_q[b * NCP + loc], 1);
    }
}

// ---------------------------------------------------------------------------
// K2: exclusive prefix scan via shfl. 8 blocks: 0-3 candidate cells,
// 4-7 query cells; 4 chunks of 4096 each (int4/thread).
// ---------------------------------------------------------------------------
__global__ __launch_bounds__(1024) void scan_chunks(
    const int* __restrict__ cc, int* __restrict__ cs, int* __restrict__ ccur,
    const int* __restrict__ qc, int* __restrict__ qs, int* __restrict__ qcur)
{
    __shared__ int wsum[16];
    __shared__ int wpre[16];
    __shared__ int ctot;
    int blk = blockIdx.x, t = (int)threadIdx.x;
    int lane = t & 63, wid = t >> 6;
    const int* cnts; int* oS; int* oC; int batch;
    if (blk < 4) { batch = blk;     cnts = cc; oS = cs; oC = ccur; }
    else         { batch = blk - 4; cnts = qc; oS = qs; oC = qcur; }
    int base = batch * NCP;
    int carry = batch * NPTS;
    for (int ch = 0; ch < NCP; ch += 4096) {
        int4 v = *(const int4*)&cnts[base + ch + t * 4];
        int tsum = v.x + v.y + v.z + v.w;
        int incl = tsum;
        #pragma unroll
        for (int o = 1; o < 64; o <<= 1) {
            int n = __shfl_up(incl, o);
            if (lane >= o) incl += n;
        }
        if (lane == 63) wsum[wid] = incl;
        __syncthreads();
        if (t < 16) {
            int wv = wsum[t];
            int wincl = wv;
            #pragma unroll
            for (int o = 1; o < 16; o <<= 1) {
                int n = __shfl_up(wincl, o);
                if (t >= o) wincl += n;
            }
            wpre[t] = wincl - wv;
            if (t == 15) ctot = wincl;
        }
        __syncthreads();
        int excl = carry + wpre[wid] + (incl - tsum);
        int4 o4; o4.x = excl; o4.y = excl + v.x; o4.z = o4.y + v.y; o4.w = o4.z + v.z;
        *(int4*)&oS[base + ch + t * 4] = o4;
        *(int4*)&oC[base + ch + t * 4] = o4;
        carry += ctot;
        __syncthreads();
    }
    if (t == 0) oS[base + NCP] = carry;   // sentinel
}

// ---------------------------------------------------------------------------
// K3: scatter candidates into cell-sorted order (key + flow).
// ---------------------------------------------------------------------------
__global__ __launch_bounds__(256) void scatter_c(
    const float* __restrict__ xyz1, const float* __restrict__ flow1,
    int* __restrict__ ccur, float4* __restrict__ ckey, float4* __restrict__ cflow)
{
    int t = blockIdx.x * 256 + threadIdx.x;
    int b = t >> 13, n = t & (NPTS - 1);
    const float* x = xyz1 + b * 3 * NPTS + n;
    const float* f = flow1 + b * 3 * NPTS + n;
    float fx = f[0], fy = f[NPTS], fz = f[2*NPTS];
    float wx = x[0] + fx, wy = x[NPTS] + fy, wz = x[2*NPTS] + fz;
    float nrm = fmaf(wx, wx, fmaf(wy, wy, wz * wz));
    int loc = (cellc(wz) * GS + cellc(wy)) * GS + cellc(wx);
    int pos = atomicAdd(&ccur[b * NCP + loc], 1);
    ckey[pos]  = make_float4(-2.0f*wx, -2.0f*wy, -2.0f*wz, nrm);
    cflow[pos] = make_float4(fx, fy, fz, 0.0f);
}

// ---------------------------------------------------------------------------
// K4: scatter queries into cell-sorted order (coords + original index).
// ---------------------------------------------------------------------------
__global__ __launch_bounds__(256) void scatter_q(
    const float* __restrict__ xyz2, int* __restrict__ qcur,
    float4* __restrict__ qpos)
{
    int t = blockIdx.x * 256 + threadIdx.x;
    int b = t >> 13, n = t & (NPTS - 1);
    const float* q = xyz2 + b * 3 * NPTS + n;
    float qx = q[0], qy = q[NPTS], qz = q[2*NPTS];
    int loc = (cellc(qz) * GS + cellc(qy)) * GS + cellc(qx);
    int pos = atomicAdd(&qcur[b * NCP + loc], 1);
    qpos[pos] = make_float4(qx, qy, qz, __int_as_float(n));
}

// ---------------------------------------------------------------------------
// K5: main pass, accumulate-then-stream (R11 structure, unchanged).
// Block = 256 thr = 32 sorted queries x 8 slot-streams. Per z-slab: active
// queries (|hz-z|<=1) define a tight y/x window; per-row offsets via 64-lane
// shfl scan; rows copied cooperatively into a 1536-slot LDS buffer that
// accumulates ACROSS slabs, streamed in long broadcast passes. Resolve via
// per-query +-1-cell-box margin (grid-edge faces skipped) -> exact.
// Unresolved queries -> compacted per-batch fallback list.
// ---------------------------------------------------------------------------
#define STREAM(lim) do {                                              \
    for (int i_ = so; i_ < (lim); i_ += 8) {                          \
        float4 c_ = sc[i_];                                           \
        int kk_ = sidx[i_];                                           \
        float d_ = fmaf(c_.x, qx, fmaf(c_.y, qy, fmaf(c_.z, qz, c_.w))); \
        INS3(d_, kk_, e0, e1, e2, i0, i1, i2);                        \
    }                                                                 \
} while (0)

__global__ __launch_bounds__(256) void knn_tile(
    const float4* __restrict__ qpos, const float4* __restrict__ ckey,
    const float4* __restrict__ cflow, const int* __restrict__ cstart,
    int* __restrict__ fbcnt, int* __restrict__ fblist, float* __restrict__ out)
{
    __shared__ float4 sc[BUF];
    __shared__ int    sidx[BUF];
    float* md = (float*)&sc[0];                       // [8][32][3], aliases sc
    int*   mi = (int*)((char*)&sc[0] + 3072);

    int tile = blockIdx.x;               // BATCH*256
    int b = tile >> 8, ti = tile & 255;
    int t = (int)threadIdx.x;
    int lane = t & 63, so = t >> 5, l = t & 31, w = t >> 6;
    int qbase = b * NPTS + ti * QPT;

    float4 qp = qpos[qbase + l];
    float qx = qp.x, qy = qp.y, qz = qp.z;
    int origj = __float_as_int(qp.w);
    float qn = fmaf(qx, qx, fmaf(qy, qy, qz * qz));
    int hx = cellc(qx), hy = cellc(qy), hz = cellc(qz);

    int zmn = hz, zmx = hz;
    #pragma unroll
    for (int o = 32; o >= 1; o >>= 1) {
        zmn = min(zmn, __shfl_xor(zmn, o));
        zmx = max(zmx, __shfl_xor(zmx, o));
    }
    int loz = max(zmn - 1, 0), hiz = min(zmx + 1, GS - 1);

    float e0 = FINF, e1 = FINF, e2 = FINF;
    int   i0 = 0, i1 = 0, i2 = 0;
    int bufofs = 0;
    int bN = b * NCP;

    for (int z = loz; z <= hiz; ++z) {
        bool act = (hz - z <= 1) && (z - hz <= 1);
        int ymn = act ? hy : 1000, ymx = act ? hy : -1000;
        int xmn = act ? hx : 1000, xmx = act ? hx : -1000;
        #pragma unroll
        for (int o = 32; o >= 1; o >>= 1) {
            ymn = min(ymn, __shfl_xor(ymn, o));
            ymx = max(ymx, __shfl_xor(ymx, o));
            xmn = min(xmn, __shfl_xor(xmn, o));
            xmx = max(xmx, __shfl_xor(xmx, o));
        }
        if (ymn == 1000) continue;                 // no query needs this slab
        int ylo = max(ymn - 1, 0), yhi = min(ymx + 1, GS - 1);
        int xlo = max(xmn - 1, 0), xhi = min(xmx + 1, GS - 1);
        int nrows = yhi - ylo + 1;                 // <= 24 < 64

        int strt = 0, rlen = 0;
        if (lane < nrows) {
            int rb = bN + (z * GS + (ylo + lane)) * GS;
            strt = cstart[rb + xlo];
            rlen = cstart[rb + xhi + 1] - strt;
        }
        int incl = rlen;
        #pragma unroll
        for (int o = 1; o < 64; o <<= 1) {
            int n = __shfl_up(incl, o);
            if (lane >= o) incl += n;
        }
        int excl = incl - rlen;
        int T = __shfl(incl, 63);

        int copied = 0;
        while (copied < T) {                       // uniform loop
            int cnt = min(T - copied, BUF - bufofs);
            for (int r = w; r < nrows; r += 4) {   // wave w copies rows w,w+4,..
                int rofs = __shfl(excl, r);
                int rst  = __shfl(strt, r);
                int rln  = __shfl(rlen, r);
                int lo = max(rofs, copied), hi = min(rofs + rln, copied + cnt);
                for (int i = lo + lane; i < hi; i += 64) {
                    int dst = bufofs + (i - copied);
                    int src = rst + (i - rofs);
                    sc[dst] = ckey[src];
                    sidx[dst] = src;
                }
            }
            bufofs += cnt; copied += cnt;
            if (bufofs == BUF) {                   // uniform
                __syncthreads();
                STREAM(BUF);
                __syncthreads();
                bufofs = 0;
            }
        }
    }
    __syncthreads();
    if (bufofs > 0) STREAM(bufofs);                // uniform
    __syncthreads();                               // sc reuse as md/mi below

    md[(so * 32 + l) * 3 + 0] = e0;  mi[(so * 32 + l) * 3 + 0] = i0;
    md[(so * 32 + l) * 3 + 1] = e1;  mi[(so * 32 + l) * 3 + 1] = i1;
    md[(so * 32 + l) * 3 + 2] = e2;  mi[(so * 32 + l) * 3 + 2] = i2;
    __syncthreads();

    if (t < 32) {
        float m0 = FINF, m1 = FINF, m2 = FINF;
        int   n0 = 0, n1 = 0, n2 = 0;
        #pragma unroll
        for (int ss = 0; ss < 8; ++ss) {
            int bx = (ss * 32 + t) * 3;
            INS3(md[bx],     mi[bx],     m0, m1, m2, n0, n1, n2);
            INS3(md[bx + 1], mi[bx + 1], m0, m1, m2, n0, n1, n2);
            INS3(md[bx + 2], mi[bx + 2], m0, m1, m2, n0, n1, n2);
        }
        // per-query margin: distance to own +-1-cell-box faces (grid-edge skipped)
        float mg = FINF;
        if (hx > 1)      mg = fminf(mg, qx - (GMIN + (hx - 1) * CS));
        if (hx < GS - 2) mg = fminf(mg, (GMIN + (hx + 2) * CS) - qx);
        if (hy > 1)      mg = fminf(mg, qy - (GMIN + (hy - 1) * CS));
        if (hy < GS - 2) mg = fminf(mg, (GMIN + (hy + 2) * CS) - qy);
        if (hz > 1)      mg = fminf(mg, qz - (GMIN + (hz - 1) * CS));
        if (hz < GS - 2) mg = fminf(mg, (GMIN + (hz + 2) * CS) - qz);
        if (m2 + qn <= mg * mg) {
            idw_write(qx, qy, qz, n0, n1, n2, ckey, cflow, out, b, origj);
        } else {
            int p = atomicAdd(&fbcnt[b], 1);
            fblist[b * NPTS + p] = ti * QPT + t;   // batch-local sorted position
        }
    }
}

// ---------------------------------------------------------------------------
// K6: wave-per-query fallback. Block = 256 thr = 4 waves = 4 queries.
// Lane ln scans candidates ln, ln+64, ... (coalesced float4 vector loads,
// 128 iters over the batch's 8192 candidates), butterfly shfl merge of
// top-3s, lane 0 does the IDW write. Worst-case grid with wave-uniform
// early exit (fallback count unknown at launch: graph capture, no readback).
// Lane-strided partition is not index-faithful on exact key ties; ties are
// measure-zero for this data (same argument as atomic scatter order).
// ---------------------------------------------------------------------------
__global__ __launch_bounds__(256) void fb_wave(
    const float4* __restrict__ qpos, const float4* __restrict__ ckey,
    const float4* __restrict__ cflow, const int* __restrict__ fbcnt,
    const int* __restrict__ fblist, float* __restrict__ out)
{
    int blk = blockIdx.x;                 // BATCH * NPTS/4 = 8192
    int b = blk >> 11, grp = blk & 2047;
    int t = (int)threadIdx.x;
    int w = t >> 6, ln = t & 63;
    int cnt = fbcnt[b];
    int idx = grp * 4 + w;
    if (idx >= cnt) return;               // wave-uniform exit

    int js = fblist[b * NPTS + idx];
    float4 qp = qpos[b * NPTS + js];
    float qx = qp.x, qy = qp.y, qz = qp.z;
    int origj = __float_as_int(qp.w);

    const float4* src = ckey + b * NPTS;

    float e0 = FINF, e1 = FINF, e2 = FINF;
    int   i0 = 0, i1 = 0, i2 = 0;
    #pragma unroll 4
    for (int k = ln; k < NPTS; k += 64) {
        float4 c = src[k];
        float d = fmaf(c.x, qx, fmaf(c.y, qy, fmaf(c.z, qz, c.w)));
        INS3(d, k, e0, e1, e2, i0, i1, i2);
    }
    // butterfly merge across 64 lanes
    #pragma unroll
    for (int o = 1; o < 64; o <<= 1) {
        float r0 = __shfl_xor(e0, o), r1 = __shfl_xor(e1, o), r2 = __shfl_xor(e2, o);
        int   s0 = __shfl_xor(i0, o), s1 = __shfl_xor(i1, o), s2 = __shfl_xor(i2, o);
        INS3(r0, s0, e0, e1, e2, i0, i1, i2);
        INS3(r1, s1, e0, e1, e2, i0, i1, i2);
        INS3(r2, s2, e0, e1, e2, i0, i1, i2);
    }
    if (ln == 0) {
        idw_write(qx, qy, qz, b * NPTS + i0, b * NPTS + i1, b * NPTS + i2,
                  ckey, cflow, out, b, origj);
    }
}

// ---------------------------------------------------------------------------
// Launcher. Workspace ~3.1 MB.
// ---------------------------------------------------------------------------
extern "C" void kernel_launch(void* const* d_in, const int* in_sizes, int n_in,
                              void* d_out, int out_size, void* d_ws, size_t ws_size,
                              hipStream_t stream)
{
    const float* xyz1  = (const float*)d_in[0];
    const float* xyz2  = (const float*)d_in[1];
    const float* flow1 = (const float*)d_in[2];
    float* out = (float*)d_out;

    char* p = (char*)d_ws;
    float4* ckey     = (float4*)p;  p += (size_t)BATCH * NPTS * 16;
    float4* cflow    = (float4*)p;  p += (size_t)BATCH * NPTS * 16;
    float4* qpos     = (float4*)p;  p += (size_t)BATCH * NPTS * 16;
    int*    counts_c = (int*)p;     p += (size_t)BATCH * NCP * 4;
    int*    counts_q = (int*)p;     p += (size_t)BATCH * NCP * 4;
    int*    fbcnt    = (int*)p;     p += 16;
    int*    cstart   = (int*)p;     p += ((size_t)BATCH * NCP + 4) * 4;
    int*    ccur     = (int*)p;     p += (size_t)BATCH * NCP * 4;
    int*    qstart   = (int*)p;     p += ((size_t)BATCH * NCP + 4) * 4;
    int*    qcur     = (int*)p;     p += (size_t)BATCH * NCP * 4;
    int*    fblist   = (int*)p;

    // zero counts_c + counts_q + fbcnt in one shot (contiguous)
    hipMemsetAsync(counts_c, 0, (size_t)BATCH * NCP * 4 * 2 + 16, stream);
    bin_both   <<<2 * BATCH * NPTS / 256, 256, 0, stream>>>(xyz1, xyz2, flow1, counts_c, counts_q);
    scan_chunks<<<8, 1024, 0, stream>>>(counts_c, cstart, ccur, counts_q, qstart, qcur);
    scatter_c  <<<BATCH * NPTS / 256, 256, 0, stream>>>(xyz1, flow1, ccur, ckey, cflow);
    scatter_q  <<<BATCH * NPTS / 256, 256, 0, stream>>>(xyz2, qcur, qpos);
    knn_tile   <<<BATCH * (NPTS / QPT), 256, 0, stream>>>(qpos, ckey, cflow, cstart, fbcnt, fblist, out);
    fb_wave    <<<BATCH * (NPTS / 4), 256, 0, stream>>>(qpos, ckey, cflow, fbcnt, fblist, out);
}